// Round 3
// baseline (312.652 us; speedup 1.0000x reference)
//
#include <hip/hip_runtime.h>
#include <stdint.h>

// Problem constants (from reference)
#define N_B   512
#define D_K   512
#define C_N   50000
#define C_PAD 50048        // padded to 391*128
#define BM    128
#define BN    128
#define BK    32
#define NCB   391          // ceil(C_N / BN)
#define NWG   (NCB * 4)    // 1564 workgroups, 1D grid

#define S_SCALE 30.0f
#define COS_Mc  0.87758256189037276f
#define SIN_Mc  0.47942553860420301f
#define TH_Cc  (-0.87758256189037276f)
#define MM_Cc   0.23971276930210156f
#define NEG_BIG (-3.0e38f)

typedef __attribute__((ext_vector_type(8))) __bf16 bf16x8;
typedef __attribute__((ext_vector_type(4))) float  f32x4;

__device__ __forceinline__ unsigned short f2bf(float f) {
    union { float f; unsigned u; } v; v.f = f;
    unsigned r = v.u + 0x7FFFu + ((v.u >> 16) & 1u);   // RNE
    return (unsigned short)(r >> 16);
}

// Unified prep: blocks [0,128) normalize x (512 rows), blocks [128,12640)
// normalize w (50048 rows incl. 48 zero-pad rows). One wave per row: exact
// fp32 inverse L2 norm + bf16 conversion. Block 0 also zeroes the loss accum.
__global__ __launch_bounds__(256) void prep_all_kernel(
        const float* __restrict__ x, unsigned short* __restrict__ xb,
        float* __restrict__ invx,
        const float* __restrict__ w, unsigned short* __restrict__ wb,
        float* __restrict__ invw, float* __restrict__ loss_out)
{
    if (blockIdx.x == 0 && threadIdx.x == 0) *loss_out = 0.f;
    int wave = threadIdx.x >> 6, lane = threadIdx.x & 63;
    const float* src; unsigned short* dstb; float* inv; int row, nvalid;
    if (blockIdx.x < 128) {
        src = x; dstb = xb; inv = invx; nvalid = N_B;
        row = blockIdx.x * 4 + wave;
    } else {
        src = w; dstb = wb; inv = invw; nvalid = C_N;
        row = (blockIdx.x - 128) * 4 + wave;
    }
    unsigned short* dst = dstb + (size_t)row * D_K + lane * 8;
    if (row < nvalid) {
        const float4* s4 = (const float4*)(src + (size_t)row * D_K) + lane * 2;
        float4 a = s4[0], b = s4[1];
        float ss = a.x*a.x + a.y*a.y + a.z*a.z + a.w*a.w
                 + b.x*b.x + b.y*b.y + b.z*b.z + b.w*b.w;
        #pragma unroll
        for (int off = 32; off >= 1; off >>= 1) ss += __shfl_xor(ss, off, 64);
        if (lane == 0) inv[row] = 1.0f / fmaxf(sqrtf(ss), 1e-12f);
        uint4 o;
        o.x = (unsigned)f2bf(a.x) | ((unsigned)f2bf(a.y) << 16);
        o.y = (unsigned)f2bf(a.z) | ((unsigned)f2bf(a.w) << 16);
        o.z = (unsigned)f2bf(b.x) | ((unsigned)f2bf(b.y) << 16);
        o.w = (unsigned)f2bf(b.z) | ((unsigned)f2bf(b.w) << 16);
        *(uint4*)dst = o;
    } else {
        *(uint4*)dst = make_uint4(0u, 0u, 0u, 0u);
        if (lane == 0) inv[row] = 0.0f;
    }
}

// 128x128 tile GEMM (B^T layout), bf16 MFMA 16x16x32.
// v4: LDS-FREE, BARRIER-FREE K-loop. Fragments are loaded global->register
// (16B bf16x8 per lane; a 16-lane group covers 16 rows x 64B -> coalesced
// 64B transactions; wm/wn-paired waves dedupe via L1; A (512KB) is L2-hot,
// B panels shared 4x by dispatch-adjacent row-blocks via the XCD swizzle).
// No __syncthreads in the K-loop => waves fully decoupled, latency hidden by
// unroll-2 ILP + 12 waves/CU TLP (LDS is only ~3.3KB of metadata).
__global__ __launch_bounds__(256, 3) void gemm_margin_kernel(
        const unsigned short* __restrict__ xb, const unsigned short* __restrict__ wb,
        const float* __restrict__ invx, const float* __restrict__ invw,
        const int* __restrict__ labels, float* __restrict__ out,
        float* __restrict__ m_part, float* __restrict__ s_part)
{
    // Bijective XCD swizzle (m204 form): NWG = 1564 = 8*195 + 4.
    const int orig = blockIdx.x;
    const int qch = NWG >> 3, rch = NWG & 7;
    const int xcd = orig & 7, idx = orig >> 3;
    const int wg = (xcd < rch ? xcd * (qch + 1)
                              : rch * (qch + 1) + (xcd - rch) * qch) + idx;
    const int cb = wg >> 2, rb = wg & 3;   // rb fastest: 4 rbs of a cb adjacent
    const int m0 = rb * BM, c0 = cb * BN;
    const int tid = threadIdx.x;
    const int lane = tid & 63, wave = tid >> 6;
    const int wm = wave >> 1, wn = wave & 1;
    const int l15 = lane & 15, q = lane >> 4;

    __shared__ float s_invx[BM];
    __shared__ float s_invw[BN];
    __shared__ int   s_lab[BM];
    __shared__ float sm[2][BM];
    __shared__ float ssm[2][BM];

    if (tid < BM) {
        s_invx[tid] = invx[m0 + tid];
        s_lab[tid]  = labels[m0 + tid];
        s_invw[tid] = invw[c0 + tid];
    }

    f32x4 zero4 = {0.f, 0.f, 0.f, 0.f};
    f32x4 acc[4][4];
    #pragma unroll
    for (int i = 0; i < 4; i++)
        #pragma unroll
        for (int j = 0; j < 4; j++) acc[i][j] = zero4;

    // Per-lane fragment bases. Fragment (mi): row = base + mi*16, k = q*8..+7
    // within each 32-wide k-tile. 16B aligned (row stride 1024B, q*16B, k0*64B).
    const unsigned short* a_base = xb + (size_t)(m0 + wm * 64 + l15) * D_K + q * 8;
    const unsigned short* b_base = wb + (size_t)(c0 + wn * 64 + l15) * D_K + q * 8;

    // Barrier-free K-loop: 16 steps of {8 global 16B loads, 16 MFMA}.
    // unroll 2: ~8 loads in flight under the previous step's MFMAs, bounded
    // VGPR (acc 64 + frags 64 + addrs ~16).
    #pragma unroll 2
    for (int k0 = 0; k0 < D_K; k0 += BK) {
        bf16x8 a[4], b[4];
        #pragma unroll
        for (int i = 0; i < 4; i++)
            a[i] = *(const bf16x8*)(a_base + (size_t)i * 16 * D_K + k0);
        #pragma unroll
        for (int i = 0; i < 4; i++)
            b[i] = *(const bf16x8*)(b_base + (size_t)i * 16 * D_K + k0);
        #pragma unroll
        for (int mi = 0; mi < 4; mi++)
            #pragma unroll
            for (int ni = 0; ni < 4; ni++)
                acc[mi][ni] = __builtin_amdgcn_mfma_f32_16x16x32_bf16(
                                  a[mi], b[ni], acc[mi][ni], 0, 0, 0);
    }

    __syncthreads();   // metadata (s_invx/s_invw/s_lab) visible for epilogue

    // Epilogue. C/D layout: col = lane&15, row = (lane>>4)*4 + reg  [m89/m91]
    #pragma unroll
    for (int mi = 0; mi < 4; mi++) {
        #pragma unroll
        for (int r = 0; r < 4; r++) {
            int lrow = wm * 64 + mi * 16 + q * 4 + r;
            int grow = m0 + lrow;
            float ivx = s_invx[lrow];
            int lab = s_lab[lrow];
            float tv[4]; bool ok[4];
            float vmax = NEG_BIG;
            #pragma unroll
            for (int ni = 0; ni < 4; ni++) {
                int lcol = wn * 64 + ni * 16 + l15;
                int gcol = c0 + lcol;
                float cosv = acc[mi][ni][r] * ivx * s_invw[lcol];
                float o;
                if (gcol == lab) {
                    float s2 = 1.0f + 1e-7f - cosv * cosv;
                    s2 = fminf(fmaxf(s2, 0.0f), 1.0f);
                    float phi = cosv * COS_Mc - sqrtf(s2) * SIN_Mc;
                    if (!(cosv > TH_Cc)) phi = cosv - MM_Cc;
                    o = S_SCALE * phi;
                } else {
                    o = S_SCALE * cosv;
                }
                ok[ni] = (gcol < C_N);
                tv[ni] = o;
                if (ok[ni]) {
                    out[(size_t)grow * C_N + gcol] = o;   // regular store: L2 merges lines
                    vmax = fmaxf(vmax, o);
                }
            }
            // Row max across the 16 lanes of the quad (covering 64 cols),
            // then one exp pass + sum reduce.
            #pragma unroll
            for (int off = 1; off < 16; off <<= 1)
                vmax = fmaxf(vmax, __shfl_xor(vmax, off, 64));
            float vs = 0.f;
            #pragma unroll
            for (int ni = 0; ni < 4; ni++)
                if (ok[ni]) vs += __expf(tv[ni] - vmax);
            #pragma unroll
            for (int off = 1; off < 16; off <<= 1)
                vs += __shfl_xor(vs, off, 64);
            if (l15 == 0) { sm[wn][lrow] = vmax; ssm[wn][lrow] = vs; }
        }
    }
    __syncthreads();
    if (tid < BM) {
        float m1 = sm[0][tid], s1 = ssm[0][tid];
        float m2 = sm[1][tid], s2 = ssm[1][tid];
        float M = fmaxf(m1, m2);
        float S = s1 * __expf(m1 - M) + s2 * __expf(m2 - M);
        m_part[(size_t)(m0 + tid) * NCB + cb] = M;
        s_part[(size_t)(m0 + tid) * NCB + cb] = S;
    }
}

// Merge the NCB col-block partials per row -> logZ -> per-row loss term,
// accumulated directly into loss_out (zeroed by prep_all) via device atomic.
__global__ void rowreduce_kernel(
        const float* __restrict__ m_part, const float* __restrict__ s_part,
        const float* __restrict__ out, const int* __restrict__ labels,
        float* __restrict__ loss_out)
{
    int row = blockIdx.x;
    int lane = threadIdx.x;   // blockDim = 64
    float m = NEG_BIG, s = 0.f;
    for (int j = lane; j < NCB; j += 64) {
        float m2 = m_part[(size_t)row * NCB + j];
        float s2 = s_part[(size_t)row * NCB + j];
        float M = fmaxf(m, m2);
        s = s * __expf(m - M) + s2 * __expf(m2 - M);
        m = M;
    }
    #pragma unroll
    for (int off = 1; off < 64; off <<= 1) {
        float om = __shfl_xor(m, off, 64);
        float os = __shfl_xor(s, off, 64);
        float M = fmaxf(m, om);
        s = s * __expf(m - M) + os * __expf(om - M);
        m = M;
    }
    if (lane == 0) {
        float logZ = m + logf(s);
        int lab = labels[row];
        atomicAdd(loss_out, (logZ - out[(size_t)row * C_N + lab]) * (1.0f / 512.0f));
    }
}

extern "C" void kernel_launch(void* const* d_in, const int* in_sizes, int n_in,
                              void* d_out, int out_size, void* d_ws, size_t ws_size,
                              hipStream_t stream)
{
    const float* x      = (const float*)d_in[0];
    const int*   labels = (const int*)d_in[1];
    const float* w      = (const float*)d_in[2];
    float* out = (float*)d_out;
    float* loss_out = out + (size_t)N_B * C_N;

    char* ws = (char*)d_ws;
    size_t off = 0;
    unsigned short* xb = (unsigned short*)(ws + off); off += (size_t)N_B * D_K * 2;     // 512 KB
    unsigned short* wb = (unsigned short*)(ws + off); off += (size_t)C_PAD * D_K * 2;   // 51.2 MB
    float* invx   = (float*)(ws + off); off += (size_t)N_B * 4;
    float* invw   = (float*)(ws + off); off += (size_t)C_PAD * 4;
    float* m_part = (float*)(ws + off); off += (size_t)N_B * NCB * 4;
    float* s_part = (float*)(ws + off); off += (size_t)N_B * NCB * 4;

    prep_all_kernel<<<128 + C_PAD / 4, 256, 0, stream>>>(x, xb, invx, w, wb, invw,
                                                         loss_out);
    gemm_margin_kernel<<<dim3(NWG), 256, 0, stream>>>(xb, wb, invx, invw, labels,
                                                      out, m_part, s_part);
    rowreduce_kernel<<<N_B, 64, 0, stream>>>(m_part, s_part, out, labels, loss_out);
}

// Round 5
// 247.617 us; speedup vs baseline: 1.2626x; 1.2626x over previous
//
#include <hip/hip_runtime.h>
#include <stdint.h>

// Problem constants (from reference)
#define N_B   512
#define D_K   512
#define C_N   50000
#define C_PAD 50048        // padded to 391*128
#define BM    256
#define BN    128
#define BK    32
#define NCB   391          // ceil(C_N / BN)
#define NWG   (NCB * 2)    // 782 workgroups (2 row-blocks), 1D grid
#define NT    16           // K-steps

#define S_SCALE 30.0f
#define COS_Mc  0.87758256189037276f
#define SIN_Mc  0.47942553860420301f
#define TH_Cc  (-0.87758256189037276f)
#define MM_Cc   0.23971276930210156f
#define NEG_BIG (-3.0e38f)

typedef __attribute__((ext_vector_type(8))) __bf16 bf16x8;
typedef __attribute__((ext_vector_type(4))) float  f32x4;

__device__ __forceinline__ unsigned short f2bf(float f) {
    union { float f; unsigned u; } v; v.f = f;
    unsigned r = v.u + 0x7FFFu + ((v.u >> 16) & 1u);   // RNE
    return (unsigned short)(r >> 16);
}

__device__ __forceinline__ void gl2lds16(const void* g, void* l) {
    __builtin_amdgcn_global_load_lds(
        (__attribute__((address_space(1))) unsigned int*)(g),
        (__attribute__((address_space(3))) unsigned int*)(l),
        16, 0, 0);
}

// Unified prep: blocks [0,128) normalize x (512 rows), blocks [128,12640)
// normalize w (50048 rows incl. 48 zero-pad rows). One wave per row: exact
// fp32 inverse L2 norm + bf16 conversion. Block 0 also zeroes the loss accum.
__global__ __launch_bounds__(256) void prep_all_kernel(
        const float* __restrict__ x, unsigned short* __restrict__ xb,
        float* __restrict__ invx,
        const float* __restrict__ w, unsigned short* __restrict__ wb,
        float* __restrict__ invw, float* __restrict__ loss_out)
{
    if (blockIdx.x == 0 && threadIdx.x == 0) *loss_out = 0.f;
    int wave = threadIdx.x >> 6, lane = threadIdx.x & 63;
    const float* src; unsigned short* dstb; float* inv; int row, nvalid;
    if (blockIdx.x < 128) {
        src = x; dstb = xb; inv = invx; nvalid = N_B;
        row = blockIdx.x * 4 + wave;
    } else {
        src = w; dstb = wb; inv = invw; nvalid = C_N;
        row = (blockIdx.x - 128) * 4 + wave;
    }
    unsigned short* dst = dstb + (size_t)row * D_K + lane * 8;
    if (row < nvalid) {
        const float4* s4 = (const float4*)(src + (size_t)row * D_K) + lane * 2;
        float4 a = s4[0], b = s4[1];
        float ss = a.x*a.x + a.y*a.y + a.z*a.z + a.w*a.w
                 + b.x*b.x + b.y*b.y + b.z*b.z + b.w*b.w;
        #pragma unroll
        for (int off = 32; off >= 1; off >>= 1) ss += __shfl_xor(ss, off, 64);
        if (lane == 0) inv[row] = 1.0f / fmaxf(sqrtf(ss), 1e-12f);
        uint4 o;
        o.x = (unsigned)f2bf(a.x) | ((unsigned)f2bf(a.y) << 16);
        o.y = (unsigned)f2bf(a.z) | ((unsigned)f2bf(a.w) << 16);
        o.z = (unsigned)f2bf(b.x) | ((unsigned)f2bf(b.y) << 16);
        o.w = (unsigned)f2bf(b.z) | ((unsigned)f2bf(b.w) << 16);
        *(uint4*)dst = o;
    } else {
        *(uint4*)dst = make_uint4(0u, 0u, 0u, 0u);
        if (lane == 0) inv[row] = 0.0f;
    }
}

// 256x128 tile GEMM (B^T layout), bf16 MFMA 16x16x32.
// v6: back to the PROVEN compiler-managed 2-phase structure (v3, passed),
// scaled to 512 threads / 8 waves per block for occupancy: LDS ~50.5KB
// (sm/ssm alias the As buffer, which is dead after the K-loop) -> up to
// 3 blocks/CU = 24 waves (vs ~8 before). Half the blocks, half the barrier
// instances. Same XOR k-chunk swizzle, XCD-bijective rb-fastest grid.
__global__ __launch_bounds__(512, 4) void gemm_margin_kernel(
        const unsigned short* __restrict__ xb, const unsigned short* __restrict__ wb,
        const float* __restrict__ invx, const float* __restrict__ invw,
        const int* __restrict__ labels, float* __restrict__ out,
        float* __restrict__ m_part, float* __restrict__ s_part)
{
    // Bijective XCD swizzle (m204 form): NWG = 782 = 8*97 + 6.
    const int orig = blockIdx.x;
    const int qch = NWG >> 3, rch = NWG & 7;
    const int xcd = orig & 7, idx = orig >> 3;
    const int wg = (xcd < rch ? xcd * (qch + 1)
                              : rch * (qch + 1) + (xcd - rch) * qch) + idx;
    const int cb = wg >> 1, rb = wg & 1;   // rb fastest: 2 rbs of a cb adjacent
    const int m0 = rb * BM, c0 = cb * BN;
    const int tid = threadIdx.x;
    const int lane = tid & 63, wave = tid >> 6;
    const int wm = wave >> 1, wn = wave & 1;      // 4 x 2 wave grid
    const int l15 = lane & 15, q = lane >> 4;

    __shared__ __align__(16) unsigned short As[2][BM * BK];   // 32 KB
    __shared__ __align__(16) unsigned short Bs[2][BN * BK];   // 16 KB
    __shared__ float s_invx[BM];
    __shared__ float s_invw[BN];
    __shared__ int   s_lab[BM];
    // sm/ssm live only AFTER the K-loop; alias the then-dead As buffer.
    float* sm  = (float*)&As[0][0];        // [2][BM]
    float* ssm = sm + 2 * BM;              // [2][BM]

    f32x4 zero4 = {0.f, 0.f, 0.f, 0.f};
    f32x4 acc[4][4];
    #pragma unroll
    for (int i = 0; i < 4; i++)
        #pragma unroll
        for (int j = 0; j < 4; j++) acc[i][j] = zero4;

    // Staging: 3 x 16B chunks per thread per K-step (A row srow, A row
    // srow+128, B row srow). LDS dest = wave-uniform base + lane*16 (byte
    // offsets tid*16 / 8192+tid*16 / tid*16). XOR k-chunk swizzle applied on
    // the GLOBAL source so the LDS dest stays identity lane order.
    const int srow   = tid >> 2;       // 0..127
    const int pchunk = tid & 3;        // physical chunk slot in LDS row
    const int lch0 = pchunk ^ ((srow >> 1) & 3);
    const int lch1 = pchunk ^ (((srow + 128) >> 1) & 3);

    const unsigned short* gA0 = xb + (size_t)(m0 + srow)       * D_K + lch0 * 8;
    const unsigned short* gA1 = xb + (size_t)(m0 + srow + 128) * D_K + lch1 * 8;
    const unsigned short* gB0 = wb + (size_t)(c0 + srow)       * D_K + lch0 * 8;

    const int offA0 = srow * BK + pchunk * 8;
    const int offA1 = (srow + 128) * BK + pchunk * 8;
    const int offB0 = srow * BK + pchunk * 8;

    // Fragment read offsets (same swizzle): A rows wm*64+i*16+l15 (0..255),
    // B rows wn*64+i*16+l15 (0..127), k = q*8..q*8+7.
    int aoff[4], boff[4];
    #pragma unroll
    for (int i = 0; i < 4; i++) {
        int Ra = wm * 64 + i * 16 + l15;
        aoff[i] = Ra * BK + (q ^ ((Ra >> 1) & 3)) * 8;
        int Rb = wn * 64 + i * 16 + l15;
        boff[i] = Rb * BK + (q ^ ((Rb >> 1) & 3)) * 8;
    }

#define STAGE(b, k0) do {                       \
        gl2lds16(gA0 + (k0), &As[b][offA0]);    \
        gl2lds16(gA1 + (k0), &As[b][offA1]);    \
        gl2lds16(gB0 + (k0), &Bs[b][offB0]);    \
    } while (0)

#define COMPUTE(b) do {                                                       \
        bf16x8 af_[4], bf_[4];                                                \
        _Pragma("unroll")                                                     \
        for (int i = 0; i < 4; i++) af_[i] = *(const bf16x8*)(&As[b][aoff[i]]); \
        _Pragma("unroll")                                                     \
        for (int i = 0; i < 4; i++) bf_[i] = *(const bf16x8*)(&Bs[b][boff[i]]); \
        _Pragma("unroll")                                                     \
        for (int mi = 0; mi < 4; mi++)                                        \
            _Pragma("unroll")                                                 \
            for (int ni = 0; ni < 4; ni++)                                    \
                acc[mi][ni] = __builtin_amdgcn_mfma_f32_16x16x32_bf16(        \
                                  af_[mi], bf_[ni], acc[mi][ni], 0, 0, 0);    \
    } while (0)

    // Prologue: stage tile 0 + metadata, full compiler-managed drain.
    STAGE(0, 0);
    if (tid < BM) {
        s_invx[tid] = invx[m0 + tid];
        s_lab[tid]  = labels[m0 + tid];
    }
    if (tid < BN) s_invw[tid] = invw[c0 + tid];
    __syncthreads();

    // 2-phase K-loop (proven in v3): prefetch next tile, compute current,
    // one __syncthreads per step. All waits compiler-managed.
    #pragma unroll
    for (int t = 0; t < NT; ++t) {
        const int cur = t & 1;
        if (t < NT - 1) STAGE(cur ^ 1, (t + 1) * BK);
        COMPUTE(cur);
        __syncthreads();
    }
#undef STAGE
#undef COMPUTE
    // As is dead from here on; sm/ssm (aliased into it) become live.

    // Epilogue. C/D layout: col = lane&15, row = (lane>>4)*4 + reg  [m89/m91]
    #pragma unroll
    for (int mi = 0; mi < 4; mi++) {
        #pragma unroll
        for (int r = 0; r < 4; r++) {
            int lrow = wm * 64 + mi * 16 + q * 4 + r;
            int grow = m0 + lrow;
            float ivx = s_invx[lrow];
            int lab = s_lab[lrow];
            float tv[4]; bool ok[4];
            float vmax = NEG_BIG;
            #pragma unroll
            for (int ni = 0; ni < 4; ni++) {
                int lcol = wn * 64 + ni * 16 + l15;
                int gcol = c0 + lcol;
                float cosv = acc[mi][ni][r] * ivx * s_invw[lcol];
                float o;
                if (gcol == lab) {
                    float s2 = 1.0f + 1e-7f - cosv * cosv;
                    s2 = fminf(fmaxf(s2, 0.0f), 1.0f);
                    float phi = cosv * COS_Mc - sqrtf(s2) * SIN_Mc;
                    if (!(cosv > TH_Cc)) phi = cosv - MM_Cc;
                    o = S_SCALE * phi;
                } else {
                    o = S_SCALE * cosv;
                }
                ok[ni] = (gcol < C_N);
                tv[ni] = o;
                if (ok[ni]) {
                    out[(size_t)grow * C_N + gcol] = o;   // L2 merges lines
                    vmax = fmaxf(vmax, o);
                }
            }
            // Row max across the 16 lanes of the quad (covering 64 cols),
            // then one exp pass + sum reduce.
            #pragma unroll
            for (int off = 1; off < 16; off <<= 1)
                vmax = fmaxf(vmax, __shfl_xor(vmax, off, 64));
            float vs = 0.f;
            #pragma unroll
            for (int ni = 0; ni < 4; ni++)
                if (ok[ni]) vs += __expf(tv[ni] - vmax);
            #pragma unroll
            for (int off = 1; off < 16; off <<= 1)
                vs += __shfl_xor(vs, off, 64);
            if (l15 == 0) { sm[wn * BM + lrow] = vmax; ssm[wn * BM + lrow] = vs; }
        }
    }
    __syncthreads();
    if (tid < BM) {
        float m1 = sm[0 * BM + tid], s1 = ssm[0 * BM + tid];
        float m2 = sm[1 * BM + tid], s2 = ssm[1 * BM + tid];
        float M = fmaxf(m1, m2);
        float S = s1 * __expf(m1 - M) + s2 * __expf(m2 - M);
        m_part[(size_t)(m0 + tid) * NCB + cb] = M;
        s_part[(size_t)(m0 + tid) * NCB + cb] = S;
    }
}

// Merge the NCB col-block partials per row -> logZ -> per-row loss term,
// accumulated directly into loss_out (zeroed by prep_all) via device atomic.
__global__ void rowreduce_kernel(
        const float* __restrict__ m_part, const float* __restrict__ s_part,
        const float* __restrict__ out, const int* __restrict__ labels,
        float* __restrict__ loss_out)
{
    int row = blockIdx.x;
    int lane = threadIdx.x;   // blockDim = 64
    float m = NEG_BIG, s = 0.f;
    for (int j = lane; j < NCB; j += 64) {
        float m2 = m_part[(size_t)row * NCB + j];
        float s2 = s_part[(size_t)row * NCB + j];
        float M = fmaxf(m, m2);
        s = s * __expf(m - M) + s2 * __expf(m2 - M);
        m = M;
    }
    #pragma unroll
    for (int off = 1; off < 64; off <<= 1) {
        float om = __shfl_xor(m, off, 64);
        float os = __shfl_xor(s, off, 64);
        float M = fmaxf(m, om);
        s = s * __expf(m - M) + os * __expf(om - M);
        m = M;
    }
    if (lane == 0) {
        float logZ = m + logf(s);
        int lab = labels[row];
        atomicAdd(loss_out, (logZ - out[(size_t)row * C_N + lab]) * (1.0f / 512.0f));
    }
}

extern "C" void kernel_launch(void* const* d_in, const int* in_sizes, int n_in,
                              void* d_out, int out_size, void* d_ws, size_t ws_size,
                              hipStream_t stream)
{
    const float* x      = (const float*)d_in[0];
    const int*   labels = (const int*)d_in[1];
    const float* w      = (const float*)d_in[2];
    float* out = (float*)d_out;
    float* loss_out = out + (size_t)N_B * C_N;

    char* ws = (char*)d_ws;
    size_t off = 0;
    unsigned short* xb = (unsigned short*)(ws + off); off += (size_t)N_B * D_K * 2;     // 512 KB
    unsigned short* wb = (unsigned short*)(ws + off); off += (size_t)C_PAD * D_K * 2;   // 51.2 MB
    float* invx   = (float*)(ws + off); off += (size_t)N_B * 4;
    float* invw   = (float*)(ws + off); off += (size_t)C_PAD * 4;
    float* m_part = (float*)(ws + off); off += (size_t)N_B * NCB * 4;
    float* s_part = (float*)(ws + off); off += (size_t)N_B * NCB * 4;

    prep_all_kernel<<<128 + C_PAD / 4, 256, 0, stream>>>(x, xb, invx, w, wb, invw,
                                                         loss_out);
    gemm_margin_kernel<<<dim3(NWG), 512, 0, stream>>>(xb, wb, invx, invw, labels,
                                                      out, m_part, s_part);
    rowreduce_kernel<<<N_B, 64, 0, stream>>>(m_part, s_part, out, labels, loss_out);
}

// Round 7
// 244.057 us; speedup vs baseline: 1.2811x; 1.0146x over previous
//
#include <hip/hip_runtime.h>
#include <stdint.h>

// Problem constants (from reference)
#define N_B   512
#define D_K   512
#define C_N   50000
#define C_PAD 50048        // padded to 391*128
#define BM    256
#define BN    128
#define BK    32
#define NCB   391          // ceil(C_N / BN)
#define NWG   (NCB * 2)    // 782 workgroups (2 row-blocks), 1D grid
#define NT    16           // K-steps

#define S_SCALE 30.0f
#define COS_Mc  0.87758256189037276f
#define SIN_Mc  0.47942553860420301f
#define TH_Cc  (-0.87758256189037276f)
#define MM_Cc   0.23971276930210156f
#define NEG_BIG (-3.0e38f)

typedef __attribute__((ext_vector_type(8))) __bf16 bf16x8;
typedef __attribute__((ext_vector_type(4))) float  f32x4;

__device__ __forceinline__ unsigned short f2bf(float f) {
    union { float f; unsigned u; } v; v.f = f;
    unsigned r = v.u + 0x7FFFu + ((v.u >> 16) & 1u);   // RNE
    return (unsigned short)(r >> 16);
}

__device__ __forceinline__ void gl2lds16(const void* g, void* l) {
    __builtin_amdgcn_global_load_lds(
        (__attribute__((address_space(1))) unsigned int*)(g),
        (__attribute__((address_space(3))) unsigned int*)(l),
        16, 0, 0);
}

// v7 prep (resubmitted unchanged — round 6 bench was an infra failure):
// 16 rows per 256-thread block, 16 lanes per row, 32 floats per lane =>
// 8 INDEPENDENT float4 loads + 8 coalesced 8B stores per lane (deep MLP
// instead of 2 dependent-wait loads). Blocks [0,32) handle x (512 rows),
// blocks [32, 32+3128) handle w (50048 rows incl. 48 pad rows).
__global__ __launch_bounds__(256) void prep_all_kernel(
        const float* __restrict__ x, unsigned short* __restrict__ xb,
        float* __restrict__ invx,
        const float* __restrict__ w, unsigned short* __restrict__ wb,
        float* __restrict__ invw)
{
    const int wave = threadIdx.x >> 6, lane = threadIdx.x & 63;
    const int l15 = lane & 15, sub = lane >> 4;   // 4 rows per wave
    const float* src; unsigned short* dstb; float* inv; int row, nvalid;
    if (blockIdx.x < 32) {
        src = x; dstb = xb; inv = invx; nvalid = N_B;
        row = blockIdx.x * 16 + wave * 4 + sub;
    } else {
        src = w; dstb = wb; inv = invw; nvalid = C_N;
        row = (blockIdx.x - 32) * 16 + wave * 4 + sub;
    }
    unsigned short* drow = dstb + (size_t)row * D_K;
    if (row < nvalid) {
        const float4* s4 = (const float4*)(src + (size_t)row * D_K);
        float4 v[8];
        #pragma unroll
        for (int k = 0; k < 8; k++) v[k] = s4[l15 + 16 * k];   // 8 indep loads
        float ss = 0.f;
        #pragma unroll
        for (int k = 0; k < 8; k++)
            ss += v[k].x * v[k].x + v[k].y * v[k].y
                + v[k].z * v[k].z + v[k].w * v[k].w;
        #pragma unroll
        for (int off = 1; off < 16; off <<= 1) ss += __shfl_xor(ss, off, 64);
        if (l15 == 0) inv[row] = 1.0f / fmaxf(sqrtf(ss), 1e-12f);
        #pragma unroll
        for (int k = 0; k < 8; k++) {
            uint2 o;
            o.x = (unsigned)f2bf(v[k].x) | ((unsigned)f2bf(v[k].y) << 16);
            o.y = (unsigned)f2bf(v[k].z) | ((unsigned)f2bf(v[k].w) << 16);
            *(uint2*)(drow + (l15 + 16 * k) * 4) = o;   // 128B/instr coalesced
        }
    } else {
        uint2 z = make_uint2(0u, 0u);
        #pragma unroll
        for (int k = 0; k < 8; k++) *(uint2*)(drow + (l15 + 16 * k) * 4) = z;
        if (l15 == 0) inv[row] = 0.0f;
    }
}

// 256x128 tile GEMM (B^T layout), bf16 MFMA 16x16x32.
// v6 structure UNCHANGED (proven 72.8us, passed): compiler-managed 2-phase
// pipeline, 512 threads / 8 waves, LDS ~50.5KB (sm/ssm alias dead As),
// XOR k-chunk swizzle, XCD-bijective rb-fastest grid.
__global__ __launch_bounds__(512, 4) void gemm_margin_kernel(
        const unsigned short* __restrict__ xb, const unsigned short* __restrict__ wb,
        const float* __restrict__ invx, const float* __restrict__ invw,
        const int* __restrict__ labels, float* __restrict__ out,
        float* __restrict__ m_part, float* __restrict__ s_part)
{
    // Bijective XCD swizzle (m204 form): NWG = 782 = 8*97 + 6.
    const int orig = blockIdx.x;
    const int qch = NWG >> 3, rch = NWG & 7;
    const int xcd = orig & 7, idx = orig >> 3;
    const int wg = (xcd < rch ? xcd * (qch + 1)
                              : rch * (qch + 1) + (xcd - rch) * qch) + idx;
    const int cb = wg >> 1, rb = wg & 1;   // rb fastest: 2 rbs of a cb adjacent
    const int m0 = rb * BM, c0 = cb * BN;
    const int tid = threadIdx.x;
    const int lane = tid & 63, wave = tid >> 6;
    const int wm = wave >> 1, wn = wave & 1;      // 4 x 2 wave grid
    const int l15 = lane & 15, q = lane >> 4;

    __shared__ __align__(16) unsigned short As[2][BM * BK];   // 32 KB
    __shared__ __align__(16) unsigned short Bs[2][BN * BK];   // 16 KB
    __shared__ float s_invx[BM];
    __shared__ float s_invw[BN];
    __shared__ int   s_lab[BM];
    // sm/ssm live only AFTER the K-loop; alias the then-dead As buffer.
    float* sm  = (float*)&As[0][0];        // [2][BM]
    float* ssm = sm + 2 * BM;              // [2][BM]

    f32x4 zero4 = {0.f, 0.f, 0.f, 0.f};
    f32x4 acc[4][4];
    #pragma unroll
    for (int i = 0; i < 4; i++)
        #pragma unroll
        for (int j = 0; j < 4; j++) acc[i][j] = zero4;

    // Staging: 3 x 16B chunks per thread per K-step (A rows srow, srow+128,
    // B row srow). LDS dest = wave-uniform base + lane*16. XOR k-chunk
    // swizzle applied on the GLOBAL source so LDS dest stays identity order.
    const int srow   = tid >> 2;       // 0..127
    const int pchunk = tid & 3;        // physical chunk slot in LDS row
    const int lch0 = pchunk ^ ((srow >> 1) & 3);
    const int lch1 = pchunk ^ (((srow + 128) >> 1) & 3);

    const unsigned short* gA0 = xb + (size_t)(m0 + srow)       * D_K + lch0 * 8;
    const unsigned short* gA1 = xb + (size_t)(m0 + srow + 128) * D_K + lch1 * 8;
    const unsigned short* gB0 = wb + (size_t)(c0 + srow)       * D_K + lch0 * 8;

    const int offA0 = srow * BK + pchunk * 8;
    const int offA1 = (srow + 128) * BK + pchunk * 8;
    const int offB0 = srow * BK + pchunk * 8;

    // Fragment read offsets (same swizzle).
    int aoff[4], boff[4];
    #pragma unroll
    for (int i = 0; i < 4; i++) {
        int Ra = wm * 64 + i * 16 + l15;
        aoff[i] = Ra * BK + (q ^ ((Ra >> 1) & 3)) * 8;
        int Rb = wn * 64 + i * 16 + l15;
        boff[i] = Rb * BK + (q ^ ((Rb >> 1) & 3)) * 8;
    }

#define STAGE(b, k0) do {                       \
        gl2lds16(gA0 + (k0), &As[b][offA0]);    \
        gl2lds16(gA1 + (k0), &As[b][offA1]);    \
        gl2lds16(gB0 + (k0), &Bs[b][offB0]);    \
    } while (0)

#define COMPUTE(b) do {                                                       \
        bf16x8 af_[4], bf_[4];                                                \
        _Pragma("unroll")                                                     \
        for (int i = 0; i < 4; i++) af_[i] = *(const bf16x8*)(&As[b][aoff[i]]); \
        _Pragma("unroll")                                                     \
        for (int i = 0; i < 4; i++) bf_[i] = *(const bf16x8*)(&Bs[b][boff[i]]); \
        _Pragma("unroll")                                                     \
        for (int mi = 0; mi < 4; mi++)                                        \
            _Pragma("unroll")                                                 \
            for (int ni = 0; ni < 4; ni++)                                    \
                acc[mi][ni] = __builtin_amdgcn_mfma_f32_16x16x32_bf16(        \
                                  af_[mi], bf_[ni], acc[mi][ni], 0, 0, 0);    \
    } while (0)

    // Prologue: stage tile 0 + metadata, full compiler-managed drain.
    STAGE(0, 0);
    if (tid < BM) {
        s_invx[tid] = invx[m0 + tid];
        s_lab[tid]  = labels[m0 + tid];
    }
    if (tid < BN) s_invw[tid] = invw[c0 + tid];
    __syncthreads();

    // 2-phase K-loop: prefetch next tile, compute current, one
    // __syncthreads per step. All waits compiler-managed.
    #pragma unroll
    for (int t = 0; t < NT; ++t) {
        const int cur = t & 1;
        if (t < NT - 1) STAGE(cur ^ 1, (t + 1) * BK);
        COMPUTE(cur);
        __syncthreads();
    }
#undef STAGE
#undef COMPUTE
    // As is dead from here on; sm/ssm (aliased into it) become live.

    // Epilogue. C/D layout: col = lane&15, row = (lane>>4)*4 + reg  [m89/m91]
    #pragma unroll
    for (int mi = 0; mi < 4; mi++) {
        #pragma unroll
        for (int r = 0; r < 4; r++) {
            int lrow = wm * 64 + mi * 16 + q * 4 + r;
            int grow = m0 + lrow;
            float ivx = s_invx[lrow];
            int lab = s_lab[lrow];
            float tv[4]; bool ok[4];
            float vmax = NEG_BIG;
            #pragma unroll
            for (int ni = 0; ni < 4; ni++) {
                int lcol = wn * 64 + ni * 16 + l15;
                int gcol = c0 + lcol;
                float cosv = acc[mi][ni][r] * ivx * s_invw[lcol];
                float o;
                if (gcol == lab) {
                    float s2 = 1.0f + 1e-7f - cosv * cosv;
                    s2 = fminf(fmaxf(s2, 0.0f), 1.0f);
                    float phi = cosv * COS_Mc - sqrtf(s2) * SIN_Mc;
                    if (!(cosv > TH_Cc)) phi = cosv - MM_Cc;
                    o = S_SCALE * phi;
                } else {
                    o = S_SCALE * cosv;
                }
                ok[ni] = (gcol < C_N);
                tv[ni] = o;
                if (ok[ni]) {
                    out[(size_t)grow * C_N + gcol] = o;   // L2 merges lines
                    vmax = fmaxf(vmax, o);
                }
            }
            #pragma unroll
            for (int off = 1; off < 16; off <<= 1)
                vmax = fmaxf(vmax, __shfl_xor(vmax, off, 64));
            float vs = 0.f;
            #pragma unroll
            for (int ni = 0; ni < 4; ni++)
                if (ok[ni]) vs += __expf(tv[ni] - vmax);
            #pragma unroll
            for (int off = 1; off < 16; off <<= 1)
                vs += __shfl_xor(vs, off, 64);
            if (l15 == 0) { sm[wn * BM + lrow] = vmax; ssm[wn * BM + lrow] = vs; }
        }
    }
    __syncthreads();
    if (tid < BM) {
        float m1 = sm[0 * BM + tid], s1 = ssm[0 * BM + tid];
        float m2 = sm[1 * BM + tid], s2 = ssm[1 * BM + tid];
        float M = fmaxf(m1, m2);
        float S = s1 * __expf(m1 - M) + s2 * __expf(m2 - M);
        m_part[(size_t)(m0 + tid) * NCB + cb] = M;
        s_part[(size_t)(m0 + tid) * NCB + cb] = S;
    }
}

// v7 rowreduce: load ALL slot pairs into registers up front (14 independent
// loads, no serial load->merge->load chain), merge in-register, shfl-reduce,
// write per-row loss term. No atomics.
__global__ void rowreduce_kernel(
        const float* __restrict__ m_part, const float* __restrict__ s_part,
        const float* __restrict__ out, const int* __restrict__ labels,
        float* __restrict__ lossp)
{
    int row = blockIdx.x;
    int lane = threadIdx.x;   // blockDim = 64
    float mv[7], sv[7];
    #pragma unroll
    for (int i = 0; i < 7; i++) {
        int j = lane + 64 * i;
        bool in = (j < NCB);
        mv[i] = in ? m_part[(size_t)row * NCB + j] : NEG_BIG;
        sv[i] = in ? s_part[(size_t)row * NCB + j] : 0.f;
    }
    float m = mv[0], s = sv[0];
    #pragma unroll
    for (int i = 1; i < 7; i++) {
        float M = fmaxf(m, mv[i]);
        s = s * __expf(m - M) + sv[i] * __expf(mv[i] - M);
        m = M;
    }
    #pragma unroll
    for (int off = 1; off < 64; off <<= 1) {
        float om = __shfl_xor(m, off, 64);
        float os = __shfl_xor(s, off, 64);
        float M = fmaxf(m, om);
        s = s * __expf(m - M) + os * __expf(om - M);
        m = M;
    }
    if (lane == 0) {
        float logZ = m + logf(s);
        int lab = labels[row];
        lossp[row] = logZ - out[(size_t)row * C_N + lab];
    }
}

__global__ void loss_kernel(const float* __restrict__ lossp, float* __restrict__ loss_out) {
    int t = threadIdx.x;   // blockDim = 256
    float v = lossp[t] + lossp[t + 256];
    #pragma unroll
    for (int off = 32; off >= 1; off >>= 1) v += __shfl_xor(v, off, 64);
    __shared__ float part[4];
    if ((t & 63) == 0) part[t >> 6] = v;
    __syncthreads();
    if (t == 0) loss_out[0] = (part[0] + part[1] + part[2] + part[3]) * (1.0f / 512.0f);
}

extern "C" void kernel_launch(void* const* d_in, const int* in_sizes, int n_in,
                              void* d_out, int out_size, void* d_ws, size_t ws_size,
                              hipStream_t stream)
{
    const float* x      = (const float*)d_in[0];
    const int*   labels = (const int*)d_in[1];
    const float* w      = (const float*)d_in[2];
    float* out = (float*)d_out;
    float* loss_out = out + (size_t)N_B * C_N;

    char* ws = (char*)d_ws;
    size_t off = 0;
    unsigned short* xb = (unsigned short*)(ws + off); off += (size_t)N_B * D_K * 2;     // 512 KB
    unsigned short* wb = (unsigned short*)(ws + off); off += (size_t)C_PAD * D_K * 2;   // 51.2 MB
    float* invx   = (float*)(ws + off); off += (size_t)N_B * 4;
    float* invw   = (float*)(ws + off); off += (size_t)C_PAD * 4;
    float* m_part = (float*)(ws + off); off += (size_t)N_B * NCB * 4;
    float* s_part = (float*)(ws + off); off += (size_t)N_B * NCB * 4;
    float* lossp  = (float*)(ws + off); off += (size_t)N_B * 4;

    prep_all_kernel<<<32 + C_PAD / 16, 256, 0, stream>>>(x, xb, invx, w, wb, invw);
    gemm_margin_kernel<<<dim3(NWG), 512, 0, stream>>>(xb, wb, invx, invw, labels,
                                                      out, m_part, s_part);
    rowreduce_kernel<<<N_B, 64, 0, stream>>>(m_part, s_part, out, labels, lossp);
    loss_kernel<<<1, 256, 0, stream>>>(lossp, loss_out);
}